// Round 7
// baseline (1456.643 us; speedup 1.0000x reference)
//
#include <hip/hip_runtime.h>
#include <hip/hip_bf16.h>
#include <math.h>

#define T_SEQ 512
#define BATCH 64
#define DIN   128
#define H     160
#define G3    480   // 3*H

typedef _Float16 half8_t __attribute__((ext_vector_type(8)));
typedef _Float16 half2_t __attribute__((ext_vector_type(2)));

__device__ __forceinline__ float sigmoidf_(float x) {
    return 1.0f / (1.0f + __expf(-x));
}
__device__ __forceinline__ float tanhf_(float x) {
    float a = fabsf(x);
    float e = __expf(2.0f * a);
    float t = 1.0f - 2.0f / (e + 1.0f);
    return copysignf(t, x);
}

// 8-element f16 dot, f32 accumulate into 4 independent accumulators.
__device__ __forceinline__ void dot8(const half8_t h, const half8_t w,
                                     float& a0, float& a1, float& a2, float& a3) {
#if __has_builtin(__builtin_amdgcn_fdot2)
    half2_t h01{h[0], h[1]}, h23{h[2], h[3]}, h45{h[4], h[5]}, h67{h[6], h[7]};
    half2_t w01{w[0], w[1]}, w23{w[2], w[3]}, w45{w[4], w[5]}, w67{w[6], w[7]};
    a0 = __builtin_amdgcn_fdot2(h01, w01, a0, false);
    a1 = __builtin_amdgcn_fdot2(h23, w23, a1, false);
    a2 = __builtin_amdgcn_fdot2(h45, w45, a2, false);
    a3 = __builtin_amdgcn_fdot2(h67, w67, a3, false);
#else
    a0 += (float)h[0] * (float)w[0] + (float)h[1] * (float)w[1];
    a1 += (float)h[2] * (float)w[2] + (float)h[3] * (float)w[3];
    a2 += (float)h[4] * (float)w[4] + (float)h[5] * (float)w[5];
    a3 += (float)h[6] * (float)w[6] + (float)h[7] * (float)w[7];
#endif
}

// ---------------- block reductions (512 threads = 8 waves) ----------------
__device__ __forceinline__ float blockReduceSum(float v, float* red) {
    #pragma unroll
    for (int off = 32; off > 0; off >>= 1) v += __shfl_down(v, off, 64);
    int wave = threadIdx.x >> 6, lane = threadIdx.x & 63;
    __syncthreads();                 // protect red from previous use
    if (lane == 0) red[wave] = v;
    __syncthreads();
    float s = red[0];
    int nw = blockDim.x >> 6;
    for (int i = 1; i < nw; ++i) s += red[i];
    return s;
}
__device__ __forceinline__ float blockReduceMax(float v, float* red) {
    #pragma unroll
    for (int off = 32; off > 0; off >>= 1) v = fmaxf(v, __shfl_down(v, off, 64));
    int wave = threadIdx.x >> 6, lane = threadIdx.x & 63;
    __syncthreads();
    if (lane == 0) red[wave] = v;
    __syncthreads();
    float s = red[0];
    int nw = blockDim.x >> 6;
    for (int i = 1; i < nw; ++i) s = fmaxf(s, red[i]);
    return s;
}

// ---------------- f32 -> f16 weight conversion (both layers, one launch) ----
__global__ __launch_bounds__(256) void cvt_weights_kernel(
    const float* __restrict__ w0, const float* __restrict__ w1,
    _Float16* __restrict__ out, int n_per)       // out: [w0 halves][w1 halves]
{
    int i = blockIdx.x * 256 + threadIdx.x;
    if (i < n_per)            out[i] = (_Float16)w0[i];
    else if (i < 2 * n_per)   out[i] = (_Float16)w1[i - n_per];
}

// ---------------- tiled fp32 GEMM: C[M,N] = A[M,K] * B[N,K]^T + bias, opt tanh ----
__global__ __launch_bounds__(256) void gemm_bias_kernel(
    const float* __restrict__ A, const float* __restrict__ B,
    const float* __restrict__ bias, float* __restrict__ C,
    int M, int N, int K, int act)
{
    const int BM = 64, BN = 64, BK = 32;
    __shared__ __align__(16) float As[BK][BM];   // k-major
    __shared__ __align__(16) float Bs[BK][BN];
    int tid  = threadIdx.x;
    int row0 = blockIdx.x * BM;
    int col0 = blockIdx.y * BN;
    int tx = tid & 15, ty = tid >> 4;
    float acc[4][4] = {};

    for (int k0 = 0; k0 < K; k0 += BK) {
        #pragma unroll
        for (int v = 0; v < 2; ++v) {
            int idx = tid + v * 256;       // 0..511 over 64 rows x 8 vec4
            int m   = idx >> 3;
            int kq  = (idx & 7) << 2;
            float4 a4 = *reinterpret_cast<const float4*>(A + (size_t)(row0 + m) * K + k0 + kq);
            As[kq + 0][m] = a4.x; As[kq + 1][m] = a4.y;
            As[kq + 2][m] = a4.z; As[kq + 3][m] = a4.w;
            float4 b4 = make_float4(0.f, 0.f, 0.f, 0.f);
            if (col0 + m < N)
                b4 = *reinterpret_cast<const float4*>(B + (size_t)(col0 + m) * K + k0 + kq);
            Bs[kq + 0][m] = b4.x; Bs[kq + 1][m] = b4.y;
            Bs[kq + 2][m] = b4.z; Bs[kq + 3][m] = b4.w;
        }
        __syncthreads();
        #pragma unroll
        for (int kk = 0; kk < BK; ++kk) {
            float4 a4 = *reinterpret_cast<const float4*>(&As[kk][ty << 2]);
            float4 b4 = *reinterpret_cast<const float4*>(&Bs[kk][tx << 2]);
            float av[4] = {a4.x, a4.y, a4.z, a4.w};
            float bv[4] = {b4.x, b4.y, b4.z, b4.w};
            #pragma unroll
            for (int i = 0; i < 4; ++i)
                #pragma unroll
                for (int j = 0; j < 4; ++j) acc[i][j] += av[i] * bv[j];
        }
        __syncthreads();
    }
    #pragma unroll
    for (int i = 0; i < 4; ++i) {
        int row = row0 + (ty << 2) + i;
        #pragma unroll
        for (int j = 0; j < 4; ++j) {
            int col = col0 + (tx << 2) + j;
            if (col < N) {
                float v = acc[i][j] + bias[col];
                if (act == 1) v = tanhf_(v);
                C[(size_t)row * N + col] = v;
            }
        }
    }
}

// ---------------- GRU recurrence: one block per (batch, dir) ----------------
// 1024 threads; thread = (row r = tid>>1, K-half = tid&1).
// Rounds 1-6 lesson: the compiler refuses to keep loop-invariant weight loads
// in registers (VGPR_Count 60/36 across variants) and re-streams 150 KB/step
// from L2 (~80 B/cyc -> ~790 ns/step -> 406 us/layer, VALUBusy 27%).
// Fix: load the 10 weight quads via VOLATILE INLINE-ASM global_load_dwordx4.
// Inline-asm results cannot be rematerialized or re-loaded -- the allocator
// must keep the 40 VGPRs live for the kernel's lifetime. waves_per_eu(4,4)
// grants the 128-VGPR budget (16 waves/block = 1 block/CU).
// xw: [B][T][960] (dir0: 0..479, dir1: 480..959), whh_h: [2][480][160] f16,
// bhh: [2][480], out: [B][T][320] (dir0 -> 0..159, dir1 -> 160..319)
__global__ __launch_bounds__(1024)
__attribute__((amdgpu_waves_per_eu(4, 4)))
void gru_kernel(
    const float* __restrict__ xw, const _Float16* __restrict__ whh_h,
    const float* __restrict__ bhh, float* __restrict__ out)
{
    int b    = blockIdx.x >> 1;
    int dir  = blockIdx.x & 1;
    int tid  = threadIdx.x;
    int r    = tid >> 1;
    int half = tid & 1;
    bool active = (tid < 2 * G3);
    int rc   = active ? r : 0;           // clamped row: all threads load safely
    __shared__ __align__(16) _Float16 h_h[H];
    __shared__ float g_s[G3];

    const _Float16* wp = whh_h + (size_t)dir * G3 * H + (size_t)rc * H + half * 80;
    float4 f0, f1, f2, f3, f4, f5, f6, f7, f8, f9;
    // volatile asm loads: compiler cannot sink/remat these; 40 VGPRs pinned.
    asm volatile("global_load_dwordx4 %0, %1, off"             : "=&v"(f0) : "v"(wp));
    asm volatile("global_load_dwordx4 %0, %1, off offset:16"   : "=&v"(f1) : "v"(wp));
    asm volatile("global_load_dwordx4 %0, %1, off offset:32"   : "=&v"(f2) : "v"(wp));
    asm volatile("global_load_dwordx4 %0, %1, off offset:48"   : "=&v"(f3) : "v"(wp));
    asm volatile("global_load_dwordx4 %0, %1, off offset:64"   : "=&v"(f4) : "v"(wp));
    asm volatile("global_load_dwordx4 %0, %1, off offset:80"   : "=&v"(f5) : "v"(wp));
    asm volatile("global_load_dwordx4 %0, %1, off offset:96"   : "=&v"(f6) : "v"(wp));
    asm volatile("global_load_dwordx4 %0, %1, off offset:112"  : "=&v"(f7) : "v"(wp));
    asm volatile("global_load_dwordx4 %0, %1, off offset:128"  : "=&v"(f8) : "v"(wp));
    asm volatile("global_load_dwordx4 %0, %1, off offset:144"  : "=&v"(f9) : "v"(wp));
    float bias = bhh[dir * G3 + rc];
    asm volatile("s_waitcnt vmcnt(0)" ::: "memory");
    __builtin_amdgcn_sched_barrier(0);
    half8_t w0 = __builtin_bit_cast(half8_t, f0);
    half8_t w1 = __builtin_bit_cast(half8_t, f1);
    half8_t w2 = __builtin_bit_cast(half8_t, f2);
    half8_t w3 = __builtin_bit_cast(half8_t, f3);
    half8_t w4 = __builtin_bit_cast(half8_t, f4);
    half8_t w5 = __builtin_bit_cast(half8_t, f5);
    half8_t w6 = __builtin_bit_cast(half8_t, f6);
    half8_t w7 = __builtin_bit_cast(half8_t, f7);
    half8_t w8 = __builtin_bit_cast(half8_t, f8);
    half8_t w9 = __builtin_bit_cast(half8_t, f9);

    if (tid < H) h_h[tid] = (_Float16)0.f;
    float hcur = 0.f;                     // this gate-thread's h element (fp32)
    __syncthreads();

    for (int step = 0; step < T_SEQ; ++step) {
        int tt = dir ? (T_SEQ - 1 - step) : step;
        size_t base = ((size_t)b * T_SEQ + tt) * 960 + (size_t)dir * G3;
        float xr = 0.f, xz = 0.f, xn = 0.f;
        if (tid < H) {   // issue early; latency hides under the dot below
            xr = xw[base + tid];
            xz = xw[base + H + tid];
            xn = xw[base + 2 * H + tid];
        }
        float a0 = 0.f, a1 = 0.f, a2 = 0.f, a3 = 0.f;
        {
            // h reads: only 2 distinct LDS addresses per wave (half=tid&1)
            // -> same-address broadcast, conflict-free.
            const half8_t* hp8 = reinterpret_cast<const half8_t*>(h_h) + half * 10;
            dot8(hp8[0], w0, a0, a1, a2, a3);
            dot8(hp8[1], w1, a0, a1, a2, a3);
            dot8(hp8[2], w2, a0, a1, a2, a3);
            dot8(hp8[3], w3, a0, a1, a2, a3);
            dot8(hp8[4], w4, a0, a1, a2, a3);
            dot8(hp8[5], w5, a0, a1, a2, a3);
            dot8(hp8[6], w6, a0, a1, a2, a3);
            dot8(hp8[7], w7, a0, a1, a2, a3);
            dot8(hp8[8], w8, a0, a1, a2, a3);
            dot8(hp8[9], w9, a0, a1, a2, a3);
        }
        float s = (a0 + a1) + (a2 + a3);
        s += __shfl_xor(s, 1);           // partner lane tid^1: full 160-dot
        if (active && half == 0) g_s[r] = s + bias;
        __syncthreads();
        if (tid < H) {
            float rg = sigmoidf_(xr + g_s[tid]);
            float z  = sigmoidf_(xz + g_s[H + tid]);
            float n  = tanhf_(xn + rg * g_s[2 * H + tid]);
            float hn = (1.0f - z) * n + z * hcur;
            hcur = hn;
            h_h[tid] = (_Float16)hn;
            out[((size_t)b * T_SEQ + tt) * 320 + (size_t)dir * H + tid] = hn;
        }
        __syncthreads();
    }
}

// ---------------- attn logits: [32768][4] = keys[tok][160] . score_w[h][160] + b ---
__global__ __launch_bounds__(256) void logits_kernel(
    const float* __restrict__ keys, const float* __restrict__ sw,
    const float* __restrict__ sb, float* __restrict__ out)
{
    int gid = blockIdx.x * 256 + threadIdx.x;
    int tok = gid >> 2, h = gid & 3;
    const float4* kr = reinterpret_cast<const float4*>(keys + (size_t)tok * H);
    const float4* wr = reinterpret_cast<const float4*>(sw + (size_t)h * H);
    float acc = 0.f;
    #pragma unroll
    for (int i = 0; i < H / 4; ++i) {
        float4 a = kr[i], w4 = wr[i];
        acc += a.x * w4.x + a.y * w4.y + a.z * w4.z + a.w * w4.w;
    }
    out[gid] = acc + sb[h];
}

// ---------------- epilogue: motion + softmax + pool + proj + LN + L2, 1 block/batch --
__global__ __launch_bounds__(512) void final_kernel(
    const float* __restrict__ x, const float* __restrict__ logits,
    const float* __restrict__ seq, const float* __restrict__ proj_w,
    const float* __restrict__ proj_b, const float* __restrict__ ln_g,
    const float* __restrict__ ln_b, float* __restrict__ out)
{
    int b   = blockIdx.x;
    int tid = threadIdx.x;
    __shared__ float ms[T_SEQ];
    __shared__ float ss[T_SEQ];
    __shared__ __align__(16) float pooled[320];
    __shared__ float red[8];

    // Phase A: motion[t] = ||x[t]-x[t-1]||, m[0]=m[1]; standardize (ddof=1)
    {
        float m = 0.f;
        if (tid >= 1) {
            const float4* xc = reinterpret_cast<const float4*>(x + ((size_t)b * T_SEQ + tid) * DIN);
            const float4* xp = reinterpret_cast<const float4*>(x + ((size_t)b * T_SEQ + tid - 1) * DIN);
            float s = 0.f;
            #pragma unroll
            for (int i = 0; i < DIN / 4; ++i) {
                float4 a = xc[i], p = xp[i];
                float dx = a.x - p.x, dy = a.y - p.y, dz = a.z - p.z, dw = a.w - p.w;
                s += dx * dx + dy * dy + dz * dz + dw * dw;
            }
            m = sqrtf(s);
        }
        ms[tid] = m;
    }
    __syncthreads();
    if (tid == 0) ms[0] = ms[1];
    __syncthreads();
    float mv   = ms[tid];
    float mean = blockReduceSum(mv, red) * (1.0f / T_SEQ);
    float var  = blockReduceSum((mv - mean) * (mv - mean), red) * (1.0f / (T_SEQ - 1));
    float mstd = (mv - mean) / (sqrtf(var) + 1e-6f);

    // Phase B: 4 softmaxes over t; s[t] = mean_h weights
    float4 lg = *reinterpret_cast<const float4*>(logits + ((size_t)b * T_SEQ + tid) * 4);
    float l[4] = {lg.x + mstd, lg.y + mstd, lg.z + mstd, lg.w + mstd};
    float ssum = 0.f;
    #pragma unroll
    for (int h = 0; h < 4; ++h) {
        float mx = blockReduceMax(l[h], red);
        float e  = __expf(l[h] - mx);
        float se = blockReduceSum(e, red);
        float wv = e / se;
        ssum += wv;
    }
    float sv = ssum * 0.25f;
    ss[tid] = sv;
    out[16384 + b * T_SEQ + tid] = sv;   // output 1: weights.mean(axis=2)
    __syncthreads();

    // Phase C: pooled[d] = sum_t seq[b,t,d] * s[t]
    if (tid < 320) {
        float acc = 0.f;
        const float* sp = seq + (size_t)b * T_SEQ * 320 + tid;
        #pragma unroll 4
        for (int t = 0; t < T_SEQ; ++t) acc += sp[(size_t)t * 320] * ss[t];
        pooled[tid] = acc;
    }
    __syncthreads();

    // Phase D: embedding = pooled . proj_w^T + b ; LN ; L2-normalize
    float e = 0.f;
    if (tid < 256) {
        const float4* pw = reinterpret_cast<const float4*>(proj_w + (size_t)tid * 320);
        const float4* pl = reinterpret_cast<const float4*>(pooled);
        float acc = 0.f;
        #pragma unroll
        for (int i = 0; i < 80; ++i) {
            float4 w4 = pw[i], p4 = pl[i];
            acc += w4.x * p4.x + w4.y * p4.y + w4.z * p4.z + w4.w * p4.w;
        }
        e = acc + proj_b[tid];
    }
    float mu = blockReduceSum(tid < 256 ? e : 0.f, red) * (1.0f / 256);
    float dv = (tid < 256) ? (e - mu) : 0.f;
    float vr = blockReduceSum(dv * dv, red) * (1.0f / 256);
    float g  = 0.f;
    if (tid < 256) g = (e - mu) * rsqrtf(vr + 1e-5f) * ln_g[tid] + ln_b[tid];
    float nrm = sqrtf(blockReduceSum(g * g, red));
    nrm = fmaxf(nrm, 1e-12f);
    if (tid < 256) out[b * 256 + tid] = g / nrm;
}

extern "C" void kernel_launch(void* const* d_in, const int* in_sizes, int n_in,
                              void* d_out, int out_size, void* d_ws, size_t ws_size,
                              hipStream_t stream) {
    const float* x       = (const float*)d_in[0];
    const float* Wih0    = (const float*)d_in[1];
    const float* Whh0    = (const float*)d_in[2];
    const float* bih0    = (const float*)d_in[3];
    const float* bhh0    = (const float*)d_in[4];
    const float* Wih1    = (const float*)d_in[5];
    const float* Whh1    = (const float*)d_in[6];
    const float* bih1    = (const float*)d_in[7];
    const float* bhh1    = (const float*)d_in[8];
    const float* key_w   = (const float*)d_in[9];
    const float* key_b   = (const float*)d_in[10];
    const float* score_w = (const float*)d_in[11];
    const float* score_b = (const float*)d_in[12];
    const float* proj_w  = (const float*)d_in[13];
    const float* proj_b  = (const float*)d_in[14];
    const float* ln_g    = (const float*)d_in[15];
    const float* ln_b    = (const float*)d_in[16];

    float* ws    = (float*)d_ws;
    float* xwbuf = ws;                        // 32768*960  = 31457280 (reused for xw1)
    float* h1    = ws + 31457280;             // 32768*320  = 10485760
    float* seq   = h1 + 10485760;             // 32768*320  = 10485760
    float* keys  = seq + 10485760;            // 32768*160  =  5242880
    float* lgts  = keys + 5242880;            // 32768*4    =   131072
    _Float16* whh_h = (_Float16*)(lgts + 131072); // 2 * 153600 halves = 614.4 KB
    float* outf  = (float*)d_out;

    const int M = BATCH * T_SEQ;              // 32768
    const int NW = 2 * G3 * H;                // 153600 elements per layer

    cvt_weights_kernel<<<(2 * NW + 255) / 256, 256, 0, stream>>>(Whh0, Whh1, whh_h, NW);
    gemm_bias_kernel<<<dim3(M / 64, 15), 256, 0, stream>>>(x,   Wih0, bih0, xwbuf, M, 960, 128, 0);
    gru_kernel<<<128, 1024, 0, stream>>>(xwbuf, whh_h,        bhh0, h1);
    gemm_bias_kernel<<<dim3(M / 64, 15), 256, 0, stream>>>(h1,  Wih1, bih1, xwbuf, M, 960, 320, 0);
    gru_kernel<<<128, 1024, 0, stream>>>(xwbuf, whh_h + NW,   bhh1, seq);
    gemm_bias_kernel<<<dim3(M / 64, 3),  256, 0, stream>>>(seq, key_w, key_b, keys, M, 160, 320, 1);
    logits_kernel<<<512, 256, 0, stream>>>(keys, score_w, score_b, lgts);
    final_kernel<<<64, 512, 0, stream>>>(x, lgts, seq, proj_w, proj_b, ln_g, ln_b, outf);
}

// Round 8
// 1206.411 us; speedup vs baseline: 1.2074x; 1.2074x over previous
//
#include <hip/hip_runtime.h>
#include <hip/hip_bf16.h>
#include <math.h>

#define T_SEQ 512
#define BATCH 64
#define DIN   128
#define H     160
#define G3    480   // 3*H

typedef _Float16 half8_t __attribute__((ext_vector_type(8)));
typedef _Float16 half4_t __attribute__((ext_vector_type(4)));
typedef _Float16 half2_t __attribute__((ext_vector_type(2)));
typedef float    f32x4   __attribute__((ext_vector_type(4)));

__device__ __forceinline__ float sigmoidf_(float x) {
    return 1.0f / (1.0f + __expf(-x));
}
__device__ __forceinline__ float tanhf_(float x) {
    float a = fabsf(x);
    float e = __expf(2.0f * a);
    float t = 1.0f - 2.0f / (e + 1.0f);
    return copysignf(t, x);
}

// 8-element f16 dot, f32 accumulate into 4 independent accumulators.
__device__ __forceinline__ void dot8(const half8_t h, const half8_t w,
                                     float& a0, float& a1, float& a2, float& a3) {
#if __has_builtin(__builtin_amdgcn_fdot2)
    half2_t h01{h[0], h[1]}, h23{h[2], h[3]}, h45{h[4], h[5]}, h67{h[6], h[7]};
    half2_t w01{w[0], w[1]}, w23{w[2], w[3]}, w45{w[4], w[5]}, w67{w[6], w[7]};
    a0 = __builtin_amdgcn_fdot2(h01, w01, a0, false);
    a1 = __builtin_amdgcn_fdot2(h23, w23, a1, false);
    a2 = __builtin_amdgcn_fdot2(h45, w45, a2, false);
    a3 = __builtin_amdgcn_fdot2(h67, w67, a3, false);
#else
    a0 += (float)h[0] * (float)w[0] + (float)h[1] * (float)w[1];
    a1 += (float)h[2] * (float)w[2] + (float)h[3] * (float)w[3];
    a2 += (float)h[4] * (float)w[4] + (float)h[5] * (float)w[5];
    a3 += (float)h[6] * (float)w[6] + (float)h[7] * (float)w[7];
#endif
}

// ---------------- block reductions (512 threads = 8 waves) ----------------
__device__ __forceinline__ float blockReduceSum(float v, float* red) {
    #pragma unroll
    for (int off = 32; off > 0; off >>= 1) v += __shfl_down(v, off, 64);
    int wave = threadIdx.x >> 6, lane = threadIdx.x & 63;
    __syncthreads();
    if (lane == 0) red[wave] = v;
    __syncthreads();
    float s = red[0];
    int nw = blockDim.x >> 6;
    for (int i = 1; i < nw; ++i) s += red[i];
    return s;
}
__device__ __forceinline__ float blockReduceMax(float v, float* red) {
    #pragma unroll
    for (int off = 32; off > 0; off >>= 1) v = fmaxf(v, __shfl_down(v, off, 64));
    int wave = threadIdx.x >> 6, lane = threadIdx.x & 63;
    __syncthreads();
    if (lane == 0) red[wave] = v;
    __syncthreads();
    float s = red[0];
    int nw = blockDim.x >> 6;
    for (int i = 1; i < nw; ++i) s = fmaxf(s, red[i]);
    return s;
}

// ---------------- f32 -> f16 conversion, vectorized x4, grid-stride ----------
__global__ __launch_bounds__(256) void cvt_f2h_kernel(
    const float* __restrict__ src, _Float16* __restrict__ dst, int n4)
{
    int i = blockIdx.x * 256 + threadIdx.x;
    int stride = gridDim.x * 256;
    for (; i < n4; i += stride) {
        float4 v = reinterpret_cast<const float4*>(src)[i];
        half4_t h = {(_Float16)v.x, (_Float16)v.y, (_Float16)v.z, (_Float16)v.w};
        reinterpret_cast<half4_t*>(dst)[i] = h;
    }
}

// ---------------- f16 MFMA GEMM: C[M,N] = A[M,K] . B[N,K]^T + bias ----------
// 256 threads = 4 waves; tile 64x64; wave w owns rows [w*16, w*16+16).
// B panel (64 rows x K f16) staged once per block in LDS (+16 f16 pad -> 4-way
// max bank conflict instead of 16-way at K=320). A-frag loaded straight from
// global: 16 B/lane, L3-resident (A is <=21 MB).
// mfma_f32_16x16x32_f16 layouts: A lane l holds A[l&15][(l>>4)*8 + j];
// B lane l holds Bmath[k=(l>>4)*8+j][col=l&15] = Bin[col][k] (Bin is [N][K]);
// C/D: col = lane&15, row = (lane>>4)*4 + reg   [m89-verified, dtype-indep].
template<int LDSK>
__global__ __launch_bounds__(256) void gemm_f16_mfma_kernel(
    const _Float16* __restrict__ A, const _Float16* __restrict__ B,
    const float* __restrict__ bias, float* __restrict__ C,
    int N, int K, int act)
{
    __shared__ _Float16 Bs[64][LDSK];
    int tid  = threadIdx.x;
    int lane = tid & 63, wave = tid >> 6;
    int row0 = blockIdx.x * 64, col0 = blockIdx.y * 64;
    int kc8 = K >> 3;
    for (int idx = tid; idx < 64 * kc8; idx += 256) {
        int rr = idx / kc8, kc = (idx - rr * kc8) << 3;
        int gcol = col0 + rr;
        half8_t v = {};
        if (gcol < N) v = *reinterpret_cast<const half8_t*>(B + (size_t)gcol * K + kc);
        *reinterpret_cast<half8_t*>(&Bs[rr][kc]) = v;
    }
    __syncthreads();

    f32x4 acc0 = {}, acc1 = {}, acc2 = {}, acc3 = {};
    int arow = row0 + wave * 16 + (lane & 15);
    int koff = (lane >> 4) << 3;
    const _Float16* ap = A + (size_t)arow * K + koff;
    int bl = lane & 15;
    for (int k0 = 0; k0 < K; k0 += 32) {
        half8_t a8 = *reinterpret_cast<const half8_t*>(ap + k0);
        half8_t b0 = *reinterpret_cast<const half8_t*>(&Bs[bl     ][k0 + koff]);
        half8_t b1 = *reinterpret_cast<const half8_t*>(&Bs[bl + 16][k0 + koff]);
        half8_t b2 = *reinterpret_cast<const half8_t*>(&Bs[bl + 32][k0 + koff]);
        half8_t b3 = *reinterpret_cast<const half8_t*>(&Bs[bl + 48][k0 + koff]);
        acc0 = __builtin_amdgcn_mfma_f32_16x16x32_f16(a8, b0, acc0, 0, 0, 0);
        acc1 = __builtin_amdgcn_mfma_f32_16x16x32_f16(a8, b1, acc1, 0, 0, 0);
        acc2 = __builtin_amdgcn_mfma_f32_16x16x32_f16(a8, b2, acc2, 0, 0, 0);
        acc3 = __builtin_amdgcn_mfma_f32_16x16x32_f16(a8, b3, acc3, 0, 0, 0);
    }

    int crow = row0 + wave * 16 + ((lane >> 4) << 2);
    int cb   = col0 + (lane & 15);
    f32x4 accs[4] = {acc0, acc1, acc2, acc3};
    #pragma unroll
    for (int j = 0; j < 4; ++j) {       // static indices after unroll (rule #20)
        int ccol = cb + j * 16;
        if (ccol < N) {
            float bv = bias[ccol];
            #pragma unroll
            for (int i = 0; i < 4; ++i) {
                float v = accs[j][i] + bv;
                if (act) v = tanhf_(v);
                C[(size_t)(crow + i) * N + ccol] = v;
            }
        }
    }
}

// ---------------- GRU recurrence: one block per (batch, dir) ----------------
// Round-7 post-mortem: pinning weights (VGPR 36->52) changed NOTHING (406->415
// us) -> the kernel is LATENCY-bound per step, not weight-stream-bound.
// Redesign: 512 threads (8 waves; halves barrier cost vs 16), one thread per
// row (160-dot = 80 v_dot2; no shfl combine), waves_per_eu(2,2) -> 256-VGPR
// budget for 80 pinned weight VGPRs (volatile asm), and one-step-ahead xW
// prefetch (cover ~= one full step ~= HBM latency).
// xw: [B][T][960] f32, whh_h: [2][480][160] f16, bhh: [2][480] f32,
// out: [B][T][320] f16 (dir0 -> 0..159, dir1 -> 160..319)
__global__ __launch_bounds__(512)
__attribute__((amdgpu_waves_per_eu(2, 2)))
void gru_kernel(
    const float* __restrict__ xw, const _Float16* __restrict__ whh_h,
    const float* __restrict__ bhh, _Float16* __restrict__ out)
{
    int b    = blockIdx.x >> 1;
    int dir  = blockIdx.x & 1;
    int tid  = threadIdx.x;
    bool active = (tid < G3);
    int rc   = active ? tid : 0;
    __shared__ __align__(16) _Float16 h_h[H];
    __shared__ float g_s[G3];

    const _Float16* wp = whh_h + (size_t)dir * G3 * H + (size_t)rc * H;
    float4 f0, f1, f2, f3, f4, f5, f6, f7, f8, f9;
    float4 f10, f11, f12, f13, f14, f15, f16, f17, f18, f19;
    asm volatile("global_load_dwordx4 %0, %1, off"            : "=&v"(f0)  : "v"(wp));
    asm volatile("global_load_dwordx4 %0, %1, off offset:16"  : "=&v"(f1)  : "v"(wp));
    asm volatile("global_load_dwordx4 %0, %1, off offset:32"  : "=&v"(f2)  : "v"(wp));
    asm volatile("global_load_dwordx4 %0, %1, off offset:48"  : "=&v"(f3)  : "v"(wp));
    asm volatile("global_load_dwordx4 %0, %1, off offset:64"  : "=&v"(f4)  : "v"(wp));
    asm volatile("global_load_dwordx4 %0, %1, off offset:80"  : "=&v"(f5)  : "v"(wp));
    asm volatile("global_load_dwordx4 %0, %1, off offset:96"  : "=&v"(f6)  : "v"(wp));
    asm volatile("global_load_dwordx4 %0, %1, off offset:112" : "=&v"(f7)  : "v"(wp));
    asm volatile("global_load_dwordx4 %0, %1, off offset:128" : "=&v"(f8)  : "v"(wp));
    asm volatile("global_load_dwordx4 %0, %1, off offset:144" : "=&v"(f9)  : "v"(wp));
    asm volatile("global_load_dwordx4 %0, %1, off offset:160" : "=&v"(f10) : "v"(wp));
    asm volatile("global_load_dwordx4 %0, %1, off offset:176" : "=&v"(f11) : "v"(wp));
    asm volatile("global_load_dwordx4 %0, %1, off offset:192" : "=&v"(f12) : "v"(wp));
    asm volatile("global_load_dwordx4 %0, %1, off offset:208" : "=&v"(f13) : "v"(wp));
    asm volatile("global_load_dwordx4 %0, %1, off offset:224" : "=&v"(f14) : "v"(wp));
    asm volatile("global_load_dwordx4 %0, %1, off offset:240" : "=&v"(f15) : "v"(wp));
    asm volatile("global_load_dwordx4 %0, %1, off offset:256" : "=&v"(f16) : "v"(wp));
    asm volatile("global_load_dwordx4 %0, %1, off offset:272" : "=&v"(f17) : "v"(wp));
    asm volatile("global_load_dwordx4 %0, %1, off offset:288" : "=&v"(f18) : "v"(wp));
    asm volatile("global_load_dwordx4 %0, %1, off offset:304" : "=&v"(f19) : "v"(wp));
    float bias = bhh[dir * G3 + rc];
    asm volatile("s_waitcnt vmcnt(0)" ::: "memory");
    __builtin_amdgcn_sched_barrier(0);
    half8_t w0  = __builtin_bit_cast(half8_t, f0);
    half8_t w1  = __builtin_bit_cast(half8_t, f1);
    half8_t w2  = __builtin_bit_cast(half8_t, f2);
    half8_t w3  = __builtin_bit_cast(half8_t, f3);
    half8_t w4  = __builtin_bit_cast(half8_t, f4);
    half8_t w5  = __builtin_bit_cast(half8_t, f5);
    half8_t w6  = __builtin_bit_cast(half8_t, f6);
    half8_t w7  = __builtin_bit_cast(half8_t, f7);
    half8_t w8  = __builtin_bit_cast(half8_t, f8);
    half8_t w9  = __builtin_bit_cast(half8_t, f9);
    half8_t w10 = __builtin_bit_cast(half8_t, f10);
    half8_t w11 = __builtin_bit_cast(half8_t, f11);
    half8_t w12 = __builtin_bit_cast(half8_t, f12);
    half8_t w13 = __builtin_bit_cast(half8_t, f13);
    half8_t w14 = __builtin_bit_cast(half8_t, f14);
    half8_t w15 = __builtin_bit_cast(half8_t, f15);
    half8_t w16 = __builtin_bit_cast(half8_t, f16);
    half8_t w17 = __builtin_bit_cast(half8_t, f17);
    half8_t w18 = __builtin_bit_cast(half8_t, f18);
    half8_t w19 = __builtin_bit_cast(half8_t, f19);

    if (tid < H) h_h[tid] = (_Float16)0.f;
    float hcur = 0.f;
    __syncthreads();

    // preload xw for step 0
    float xr = 0.f, xz = 0.f, xn = 0.f;
    {
        int tt0 = dir ? (T_SEQ - 1) : 0;
        size_t base0 = ((size_t)b * T_SEQ + tt0) * 960 + (size_t)dir * G3;
        if (tid < H) {
            xr = xw[base0 + tid];
            xz = xw[base0 + H + tid];
            xn = xw[base0 + 2 * H + tid];
        }
    }

    for (int step = 0; step < T_SEQ; ++step) {
        int tt = dir ? (T_SEQ - 1 - step) : step;
        // prefetch step+1's xW: ~900-cyc HBM latency hides under the rest of
        // this step (dot+gates+barriers) + next step's dot.
        float nxr = 0.f, nxz = 0.f, nxn = 0.f;
        {
            int sn  = (step + 1 < T_SEQ) ? step + 1 : step;
            int ttn = dir ? (T_SEQ - 1 - sn) : sn;
            size_t basen = ((size_t)b * T_SEQ + ttn) * 960 + (size_t)dir * G3;
            if (tid < H) {
                nxr = xw[basen + tid];
                nxz = xw[basen + H + tid];
                nxn = xw[basen + 2 * H + tid];
            }
        }
        // 160-long dot: 80 v_dot2, 4 ILP accumulators. All lanes read the
        // same h chunk sequence -> wave-uniform LDS broadcast, conflict-free.
        float a0 = 0.f, a1 = 0.f, a2 = 0.f, a3 = 0.f;
        {
            const half8_t* hp8 = reinterpret_cast<const half8_t*>(h_h);
            dot8(hp8[0],  w0,  a0, a1, a2, a3);
            dot8(hp8[1],  w1,  a0, a1, a2, a3);
            dot8(hp8[2],  w2,  a0, a1, a2, a3);
            dot8(hp8[3],  w3,  a0, a1, a2, a3);
            dot8(hp8[4],  w4,  a0, a1, a2, a3);
            dot8(hp8[5],  w5,  a0, a1, a2, a3);
            dot8(hp8[6],  w6,  a0, a1, a2, a3);
            dot8(hp8[7],  w7,  a0, a1, a2, a3);
            dot8(hp8[8],  w8,  a0, a1, a2, a3);
            dot8(hp8[9],  w9,  a0, a1, a2, a3);
            dot8(hp8[10], w10, a0, a1, a2, a3);
            dot8(hp8[11], w11, a0, a1, a2, a3);
            dot8(hp8[12], w12, a0, a1, a2, a3);
            dot8(hp8[13], w13, a0, a1, a2, a3);
            dot8(hp8[14], w14, a0, a1, a2, a3);
            dot8(hp8[15], w15, a0, a1, a2, a3);
            dot8(hp8[16], w16, a0, a1, a2, a3);
            dot8(hp8[17], w17, a0, a1, a2, a3);
            dot8(hp8[18], w18, a0, a1, a2, a3);
            dot8(hp8[19], w19, a0, a1, a2, a3);
        }
        if (active) g_s[tid] = (a0 + a1) + (a2 + a3) + bias;
        __syncthreads();
        if (tid < H) {
            float rg = sigmoidf_(xr + g_s[tid]);
            float z  = sigmoidf_(xz + g_s[H + tid]);
            float n  = tanhf_(xn + rg * g_s[2 * H + tid]);
            float hn = (1.0f - z) * n + z * hcur;
            hcur = hn;
            h_h[tid] = (_Float16)hn;
            out[((size_t)b * T_SEQ + tt) * 320 + (size_t)dir * H + tid] = (_Float16)hn;
        }
        __syncthreads();
        xr = nxr; xz = nxz; xn = nxn;
    }
}

// ---------------- attn logits: [32768][4] = keys[tok][160] . score_w[h][160] + b ---
__global__ __launch_bounds__(256) void logits_kernel(
    const float* __restrict__ keys, const float* __restrict__ sw,
    const float* __restrict__ sb, float* __restrict__ out)
{
    int gid = blockIdx.x * 256 + threadIdx.x;
    int tok = gid >> 2, h = gid & 3;
    const float4* kr = reinterpret_cast<const float4*>(keys + (size_t)tok * H);
    const float4* wr = reinterpret_cast<const float4*>(sw + (size_t)h * H);
    float acc = 0.f;
    #pragma unroll
    for (int i = 0; i < H / 4; ++i) {
        float4 a = kr[i], w4 = wr[i];
        acc += a.x * w4.x + a.y * w4.y + a.z * w4.z + a.w * w4.w;
    }
    out[gid] = acc + sb[h];
}

// ---------------- epilogue: motion + softmax + pool + proj + LN + L2, 1 block/batch --
__global__ __launch_bounds__(512) void final_kernel(
    const float* __restrict__ x, const float* __restrict__ logits,
    const _Float16* __restrict__ seq, const float* __restrict__ proj_w,
    const float* __restrict__ proj_b, const float* __restrict__ ln_g,
    const float* __restrict__ ln_b, float* __restrict__ out)
{
    int b   = blockIdx.x;
    int tid = threadIdx.x;
    __shared__ float ms[T_SEQ];
    __shared__ float ss[T_SEQ];
    __shared__ __align__(16) float pooled[320];
    __shared__ float red[8];

    // Phase A: motion[t] = ||x[t]-x[t-1]||, m[0]=m[1]; standardize (ddof=1)
    {
        float m = 0.f;
        if (tid >= 1) {
            const float4* xc = reinterpret_cast<const float4*>(x + ((size_t)b * T_SEQ + tid) * DIN);
            const float4* xp = reinterpret_cast<const float4*>(x + ((size_t)b * T_SEQ + tid - 1) * DIN);
            float s = 0.f;
            #pragma unroll
            for (int i = 0; i < DIN / 4; ++i) {
                float4 a = xc[i], p = xp[i];
                float dx = a.x - p.x, dy = a.y - p.y, dz = a.z - p.z, dw = a.w - p.w;
                s += dx * dx + dy * dy + dz * dz + dw * dw;
            }
            m = sqrtf(s);
        }
        ms[tid] = m;
    }
    __syncthreads();
    if (tid == 0) ms[0] = ms[1];
    __syncthreads();
    float mv   = ms[tid];
    float mean = blockReduceSum(mv, red) * (1.0f / T_SEQ);
    float var  = blockReduceSum((mv - mean) * (mv - mean), red) * (1.0f / (T_SEQ - 1));
    float mstd = (mv - mean) / (sqrtf(var) + 1e-6f);

    // Phase B: 4 softmaxes over t; s[t] = mean_h weights
    float4 lg = *reinterpret_cast<const float4*>(logits + ((size_t)b * T_SEQ + tid) * 4);
    float l[4] = {lg.x + mstd, lg.y + mstd, lg.z + mstd, lg.w + mstd};
    float ssum = 0.f;
    #pragma unroll
    for (int h = 0; h < 4; ++h) {
        float mx = blockReduceMax(l[h], red);
        float e  = __expf(l[h] - mx);
        float se = blockReduceSum(e, red);
        float wv = e / se;
        ssum += wv;
    }
    float sv = ssum * 0.25f;
    ss[tid] = sv;
    out[16384 + b * T_SEQ + tid] = sv;   // output 1: weights.mean(axis=2)
    __syncthreads();

    // Phase C: pooled[d] = sum_t seq[b,t,d] * s[t]  (seq is f16)
    if (tid < 320) {
        float acc = 0.f;
        const _Float16* sp = seq + (size_t)b * T_SEQ * 320 + tid;
        #pragma unroll 4
        for (int t = 0; t < T_SEQ; ++t) acc += (float)sp[(size_t)t * 320] * ss[t];
        pooled[tid] = acc;
    }
    __syncthreads();

    // Phase D: embedding = pooled . proj_w^T + b ; LN ; L2-normalize
    float e = 0.f;
    if (tid < 256) {
        const float4* pw = reinterpret_cast<const float4*>(proj_w + (size_t)tid * 320);
        const float4* pl = reinterpret_cast<const float4*>(pooled);
        float acc = 0.f;
        #pragma unroll
        for (int i = 0; i < 80; ++i) {
            float4 w4 = pw[i], p4 = pl[i];
            acc += w4.x * p4.x + w4.y * p4.y + w4.z * p4.z + w4.w * p4.w;
        }
        e = acc + proj_b[tid];
    }
    float mu = blockReduceSum(tid < 256 ? e : 0.f, red) * (1.0f / 256);
    float dv = (tid < 256) ? (e - mu) : 0.f;
    float vr = blockReduceSum(dv * dv, red) * (1.0f / 256);
    float g  = 0.f;
    if (tid < 256) g = (e - mu) * rsqrtf(vr + 1e-5f) * ln_g[tid] + ln_b[tid];
    float nrm = sqrtf(blockReduceSum(g * g, red));
    nrm = fmaxf(nrm, 1e-12f);
    if (tid < 256) out[b * 256 + tid] = g / nrm;
}

extern "C" void kernel_launch(void* const* d_in, const int* in_sizes, int n_in,
                              void* d_out, int out_size, void* d_ws, size_t ws_size,
                              hipStream_t stream) {
    const float* x       = (const float*)d_in[0];
    const float* Wih0    = (const float*)d_in[1];
    const float* Whh0    = (const float*)d_in[2];
    const float* bih0    = (const float*)d_in[3];
    const float* bhh0    = (const float*)d_in[4];
    const float* Wih1    = (const float*)d_in[5];
    const float* Whh1    = (const float*)d_in[6];
    const float* bih1    = (const float*)d_in[7];
    const float* bhh1    = (const float*)d_in[8];
    const float* key_w   = (const float*)d_in[9];
    const float* key_b   = (const float*)d_in[10];
    const float* score_w = (const float*)d_in[11];
    const float* score_b = (const float*)d_in[12];
    const float* proj_w  = (const float*)d_in[13];
    const float* proj_b  = (const float*)d_in[14];
    const float* ln_g    = (const float*)d_in[15];
    const float* ln_b    = (const float*)d_in[16];

    const int M  = BATCH * T_SEQ;             // 32768
    const int NW = 2 * G3 * H;                // 153600 per GRU layer

    float* ws    = (float*)d_ws;
    float* xwbuf = ws;                        // 31457280 f
    float* keys  = xwbuf + 31457280;          //  5242880 f
    float* lgts  = keys + 5242880;            //   131072 f
    _Float16* h1_h   = (_Float16*)(lgts + 131072);   // 10485760 h = 5242880 f
    _Float16* seq_h  = h1_h + 10485760;              // 10485760 h
    _Float16* x_h    = seq_h + 10485760;             //  4194304 h
    _Float16* whh_h  = x_h + 4194304;                //   307200 h (both layers)
    _Float16* wih0_h = whh_h + 2 * NW;               //   122880 h
    _Float16* wih1_h = wih0_h + 122880;              //   307200 h
    _Float16* keyw_h = wih1_h + 307200;              //    51200 h
    float* outf  = (float*)d_out;

    // f32 -> f16 conversions (weights + x), all independent
    cvt_f2h_kernel<<<150, 256, 0, stream>>>(Whh0, whh_h, NW / 4);
    cvt_f2h_kernel<<<150, 256, 0, stream>>>(Whh1, whh_h + NW, NW / 4);
    cvt_f2h_kernel<<<120, 256, 0, stream>>>(Wih0, wih0_h, 122880 / 4);
    cvt_f2h_kernel<<<300, 256, 0, stream>>>(Wih1, wih1_h, 307200 / 4);
    cvt_f2h_kernel<<<50,  256, 0, stream>>>(key_w, keyw_h, 51200 / 4);
    cvt_f2h_kernel<<<2048, 256, 0, stream>>>(x, x_h, 4194304 / 4);

    gemm_f16_mfma_kernel<144><<<dim3(M / 64, 15), 256, 0, stream>>>(
        x_h, wih0_h, bih0, xwbuf, 960, 128, 0);
    gru_kernel<<<128, 512, 0, stream>>>(xwbuf, whh_h, bhh0, h1_h);
    gemm_f16_mfma_kernel<336><<<dim3(M / 64, 15), 256, 0, stream>>>(
        h1_h, wih1_h, bih1, xwbuf, 960, 320, 0);
    gru_kernel<<<128, 512, 0, stream>>>(xwbuf, whh_h + NW, bhh1, seq_h);
    gemm_f16_mfma_kernel<336><<<dim3(M / 64, 3), 256, 0, stream>>>(
        seq_h, keyw_h, key_b, keys, 160, 320, 1);
    logits_kernel<<<512, 256, 0, stream>>>(keys, score_w, score_b, lgts);
    final_kernel<<<64, 512, 0, stream>>>(x, lgts, seq_h, proj_w, proj_b, ln_g, ln_b, outf);
}

// Round 9
// 1198.403 us; speedup vs baseline: 1.2155x; 1.0067x over previous
//
#include <hip/hip_runtime.h>
#include <hip/hip_bf16.h>
#include <math.h>

#define T_SEQ 512
#define BATCH 64
#define DIN   128
#define H     160
#define G3    480   // 3*H

typedef _Float16 half8_t __attribute__((ext_vector_type(8)));
typedef _Float16 half4_t __attribute__((ext_vector_type(4)));
typedef _Float16 half2_t __attribute__((ext_vector_type(2)));
typedef float    f32x4   __attribute__((ext_vector_type(4)));

__device__ __forceinline__ float sigmoidf_(float x) {
    return 1.0f / (1.0f + __expf(-x));
}
__device__ __forceinline__ float tanhf_(float x) {
    float a = fabsf(x);
    float e = __expf(2.0f * a);
    float t = 1.0f - 2.0f / (e + 1.0f);
    return copysignf(t, x);
}

// 8-element f16 dot, f32 accumulate into 4 independent accumulators.
__device__ __forceinline__ void dot8(const half8_t h, const half8_t w,
                                     float& a0, float& a1, float& a2, float& a3) {
#if __has_builtin(__builtin_amdgcn_fdot2)
    half2_t h01{h[0], h[1]}, h23{h[2], h[3]}, h45{h[4], h[5]}, h67{h[6], h[7]};
    half2_t w01{w[0], w[1]}, w23{w[2], w[3]}, w45{w[4], w[5]}, w67{w[6], w[7]};
    a0 = __builtin_amdgcn_fdot2(h01, w01, a0, false);
    a1 = __builtin_amdgcn_fdot2(h23, w23, a1, false);
    a2 = __builtin_amdgcn_fdot2(h45, w45, a2, false);
    a3 = __builtin_amdgcn_fdot2(h67, w67, a3, false);
#else
    a0 += (float)h[0] * (float)w[0] + (float)h[1] * (float)w[1];
    a1 += (float)h[2] * (float)w[2] + (float)h[3] * (float)w[3];
    a2 += (float)h[4] * (float)w[4] + (float)h[5] * (float)w[5];
    a3 += (float)h[6] * (float)w[6] + (float)h[7] * (float)w[7];
#endif
}

// ---------------- block reductions ----------------
__device__ __forceinline__ float blockReduceSum(float v, float* red) {
    #pragma unroll
    for (int off = 32; off > 0; off >>= 1) v += __shfl_down(v, off, 64);
    int wave = threadIdx.x >> 6, lane = threadIdx.x & 63;
    __syncthreads();
    if (lane == 0) red[wave] = v;
    __syncthreads();
    float s = red[0];
    int nw = blockDim.x >> 6;
    for (int i = 1; i < nw; ++i) s += red[i];
    return s;
}
__device__ __forceinline__ float blockReduceMax(float v, float* red) {
    #pragma unroll
    for (int off = 32; off > 0; off >>= 1) v = fmaxf(v, __shfl_down(v, off, 64));
    int wave = threadIdx.x >> 6, lane = threadIdx.x & 63;
    __syncthreads();
    if (lane == 0) red[wave] = v;
    __syncthreads();
    float s = red[0];
    int nw = blockDim.x >> 6;
    for (int i = 1; i < nw; ++i) s = fmaxf(s, red[i]);
    return s;
}

// ---------------- f32 -> f16 conversion, vectorized x4, grid-stride ----------
__global__ __launch_bounds__(256) void cvt_f2h_kernel(
    const float* __restrict__ src, _Float16* __restrict__ dst, int n4)
{
    int i = blockIdx.x * 256 + threadIdx.x;
    int stride = gridDim.x * 256;
    for (; i < n4; i += stride) {
        float4 v = reinterpret_cast<const float4*>(src)[i];
        half4_t h = {(_Float16)v.x, (_Float16)v.y, (_Float16)v.z, (_Float16)v.w};
        reinterpret_cast<half4_t*>(dst)[i] = h;
    }
}

// ---------------- f16 MFMA GEMM: C[M,N] = A[M,K] . B[N,K]^T + bias ----------
// (unchanged from round 8 -- verified, absmax 9.8e-4)
template<int LDSK>
__global__ __launch_bounds__(256) void gemm_f16_mfma_kernel(
    const _Float16* __restrict__ A, const _Float16* __restrict__ B,
    const float* __restrict__ bias, float* __restrict__ C,
    int N, int K, int act)
{
    __shared__ _Float16 Bs[64][LDSK];
    int tid  = threadIdx.x;
    int lane = tid & 63, wave = tid >> 6;
    int row0 = blockIdx.x * 64, col0 = blockIdx.y * 64;
    int kc8 = K >> 3;
    for (int idx = tid; idx < 64 * kc8; idx += 256) {
        int rr = idx / kc8, kc = (idx - rr * kc8) << 3;
        int gcol = col0 + rr;
        half8_t v = {};
        if (gcol < N) v = *reinterpret_cast<const half8_t*>(B + (size_t)gcol * K + kc);
        *reinterpret_cast<half8_t*>(&Bs[rr][kc]) = v;
    }
    __syncthreads();

    f32x4 acc0 = {}, acc1 = {}, acc2 = {}, acc3 = {};
    int arow = row0 + wave * 16 + (lane & 15);
    int koff = (lane >> 4) << 3;
    const _Float16* ap = A + (size_t)arow * K + koff;
    int bl = lane & 15;
    for (int k0 = 0; k0 < K; k0 += 32) {
        half8_t a8 = *reinterpret_cast<const half8_t*>(ap + k0);
        half8_t b0 = *reinterpret_cast<const half8_t*>(&Bs[bl     ][k0 + koff]);
        half8_t b1 = *reinterpret_cast<const half8_t*>(&Bs[bl + 16][k0 + koff]);
        half8_t b2 = *reinterpret_cast<const half8_t*>(&Bs[bl + 32][k0 + koff]);
        half8_t b3 = *reinterpret_cast<const half8_t*>(&Bs[bl + 48][k0 + koff]);
        acc0 = __builtin_amdgcn_mfma_f32_16x16x32_f16(a8, b0, acc0, 0, 0, 0);
        acc1 = __builtin_amdgcn_mfma_f32_16x16x32_f16(a8, b1, acc1, 0, 0, 0);
        acc2 = __builtin_amdgcn_mfma_f32_16x16x32_f16(a8, b2, acc2, 0, 0, 0);
        acc3 = __builtin_amdgcn_mfma_f32_16x16x32_f16(a8, b3, acc3, 0, 0, 0);
    }

    int crow = row0 + wave * 16 + ((lane >> 4) << 2);
    int cb   = col0 + (lane & 15);
    f32x4 accs[4] = {acc0, acc1, acc2, acc3};
    #pragma unroll
    for (int j = 0; j < 4; ++j) {
        int ccol = cb + j * 16;
        if (ccol < N) {
            float bv = bias[ccol];
            #pragma unroll
            for (int i = 0; i < 4; ++i) {
                float v = accs[j][i] + bv;
                if (act) v = tanhf_(v);
                C[(size_t)(crow + i) * N + ccol] = v;
            }
        }
    }
}

// ---------------- GRU recurrence: one block per (batch, dir) ----------------
// Round-8 diagnosis: broadcast h-reads are LDS-THROUGHPUT-bound. A wave-wide
// ds_read_b128 costs ~8 cyc of register-fill BW even when all lanes read the
// same address; per step cost = waves x 20 reads x 8 cyc = 1280 cyc for BOTH
// the 16-wave (10 rds) and 8-wave (20 rds) variants -- invariant, matching the
// observed ~2000-cyc steps while VALU sits at ~470 cyc.
// Fix: amortize each broadcast read over 2 rows. 256 threads (4 waves), thread
// t owns rows t and t+240: LDS/step = 4x20x8 = 640 cyc (2x less), VALU = 160
// dot2 = 320 cyc/SIMD (separate pipe, overlaps). Weights 2x20 half8 = 160
// VGPRs pinned via volatile asm (proven in R7/R8); waves_per_eu(1,1) grants
// the 512-VGPR budget.
// xw: [B][T][960] f32, whh_h: [2][480][160] f16, bhh: [2][480] f32,
// out: [B][T][320] f16 (dir0 -> 0..159, dir1 -> 160..319)
#define GLD(dst, ptr, OFF) \
    asm volatile("global_load_dwordx4 %0, %1, off offset:" OFF : "=&v"(dst) : "v"(ptr))

__global__ __launch_bounds__(256)
__attribute__((amdgpu_waves_per_eu(1, 1)))
void gru_kernel(
    const float* __restrict__ xw, const _Float16* __restrict__ whh_h,
    const float* __restrict__ bhh, _Float16* __restrict__ out)
{
    int b    = blockIdx.x >> 1;
    int dir  = blockIdx.x & 1;
    int tid  = threadIdx.x;
    bool rowact = (tid < 240);
    int r0 = rowact ? tid : 0;
    int r1 = rowact ? tid + 240 : 0;
    __shared__ __align__(16) _Float16 h_h[H];
    __shared__ float g_s[G3];

    const _Float16* wbase = whh_h + (size_t)dir * G3 * H;
    const _Float16* wpA = wbase + (size_t)r0 * H;
    const _Float16* wpB = wbase + (size_t)r1 * H;
    float4 fa0, fa1, fa2, fa3, fa4, fa5, fa6, fa7, fa8, fa9;
    float4 fa10, fa11, fa12, fa13, fa14, fa15, fa16, fa17, fa18, fa19;
    float4 fb0, fb1, fb2, fb3, fb4, fb5, fb6, fb7, fb8, fb9;
    float4 fb10, fb11, fb12, fb13, fb14, fb15, fb16, fb17, fb18, fb19;
    GLD(fa0,  wpA, "0");   GLD(fa1,  wpA, "16");  GLD(fa2,  wpA, "32");
    GLD(fa3,  wpA, "48");  GLD(fa4,  wpA, "64");  GLD(fa5,  wpA, "80");
    GLD(fa6,  wpA, "96");  GLD(fa7,  wpA, "112"); GLD(fa8,  wpA, "128");
    GLD(fa9,  wpA, "144"); GLD(fa10, wpA, "160"); GLD(fa11, wpA, "176");
    GLD(fa12, wpA, "192"); GLD(fa13, wpA, "208"); GLD(fa14, wpA, "224");
    GLD(fa15, wpA, "240"); GLD(fa16, wpA, "256"); GLD(fa17, wpA, "272");
    GLD(fa18, wpA, "288"); GLD(fa19, wpA, "304");
    GLD(fb0,  wpB, "0");   GLD(fb1,  wpB, "16");  GLD(fb2,  wpB, "32");
    GLD(fb3,  wpB, "48");  GLD(fb4,  wpB, "64");  GLD(fb5,  wpB, "80");
    GLD(fb6,  wpB, "96");  GLD(fb7,  wpB, "112"); GLD(fb8,  wpB, "128");
    GLD(fb9,  wpB, "144"); GLD(fb10, wpB, "160"); GLD(fb11, wpB, "176");
    GLD(fb12, wpB, "192"); GLD(fb13, wpB, "208"); GLD(fb14, wpB, "224");
    GLD(fb15, wpB, "240"); GLD(fb16, wpB, "256"); GLD(fb17, wpB, "272");
    GLD(fb18, wpB, "288"); GLD(fb19, wpB, "304");
    float biasA = bhh[dir * G3 + r0];
    float biasB = bhh[dir * G3 + r1];
    asm volatile("s_waitcnt vmcnt(0)" ::: "memory");
    __builtin_amdgcn_sched_barrier(0);
    half8_t wa0  = __builtin_bit_cast(half8_t, fa0);
    half8_t wa1  = __builtin_bit_cast(half8_t, fa1);
    half8_t wa2  = __builtin_bit_cast(half8_t, fa2);
    half8_t wa3  = __builtin_bit_cast(half8_t, fa3);
    half8_t wa4  = __builtin_bit_cast(half8_t, fa4);
    half8_t wa5  = __builtin_bit_cast(half8_t, fa5);
    half8_t wa6  = __builtin_bit_cast(half8_t, fa6);
    half8_t wa7  = __builtin_bit_cast(half8_t, fa7);
    half8_t wa8  = __builtin_bit_cast(half8_t, fa8);
    half8_t wa9  = __builtin_bit_cast(half8_t, fa9);
    half8_t wa10 = __builtin_bit_cast(half8_t, fa10);
    half8_t wa11 = __builtin_bit_cast(half8_t, fa11);
    half8_t wa12 = __builtin_bit_cast(half8_t, fa12);
    half8_t wa13 = __builtin_bit_cast(half8_t, fa13);
    half8_t wa14 = __builtin_bit_cast(half8_t, fa14);
    half8_t wa15 = __builtin_bit_cast(half8_t, fa15);
    half8_t wa16 = __builtin_bit_cast(half8_t, fa16);
    half8_t wa17 = __builtin_bit_cast(half8_t, fa17);
    half8_t wa18 = __builtin_bit_cast(half8_t, fa18);
    half8_t wa19 = __builtin_bit_cast(half8_t, fa19);
    half8_t wb0  = __builtin_bit_cast(half8_t, fb0);
    half8_t wb1  = __builtin_bit_cast(half8_t, fb1);
    half8_t wb2  = __builtin_bit_cast(half8_t, fb2);
    half8_t wb3  = __builtin_bit_cast(half8_t, fb3);
    half8_t wb4  = __builtin_bit_cast(half8_t, fb4);
    half8_t wb5  = __builtin_bit_cast(half8_t, fb5);
    half8_t wb6  = __builtin_bit_cast(half8_t, fb6);
    half8_t wb7  = __builtin_bit_cast(half8_t, fb7);
    half8_t wb8  = __builtin_bit_cast(half8_t, fb8);
    half8_t wb9  = __builtin_bit_cast(half8_t, fb9);
    half8_t wb10 = __builtin_bit_cast(half8_t, fb10);
    half8_t wb11 = __builtin_bit_cast(half8_t, fb11);
    half8_t wb12 = __builtin_bit_cast(half8_t, fb12);
    half8_t wb13 = __builtin_bit_cast(half8_t, fb13);
    half8_t wb14 = __builtin_bit_cast(half8_t, fb14);
    half8_t wb15 = __builtin_bit_cast(half8_t, fb15);
    half8_t wb16 = __builtin_bit_cast(half8_t, fb16);
    half8_t wb17 = __builtin_bit_cast(half8_t, fb17);
    half8_t wb18 = __builtin_bit_cast(half8_t, fb18);
    half8_t wb19 = __builtin_bit_cast(half8_t, fb19);

    if (tid < H) h_h[tid] = (_Float16)0.f;
    float hcur = 0.f;
    __syncthreads();

    // preload xw for step 0
    float xr = 0.f, xz = 0.f, xn = 0.f;
    {
        int tt0 = dir ? (T_SEQ - 1) : 0;
        size_t base0 = ((size_t)b * T_SEQ + tt0) * 960 + (size_t)dir * G3;
        if (tid < H) {
            xr = xw[base0 + tid];
            xz = xw[base0 + H + tid];
            xn = xw[base0 + 2 * H + tid];
        }
    }

    for (int step = 0; step < T_SEQ; ++step) {
        int tt = dir ? (T_SEQ - 1 - step) : step;
        // prefetch step+1's xW (HBM latency hides under this step)
        float nxr = 0.f, nxz = 0.f, nxn = 0.f;
        {
            int sn  = (step + 1 < T_SEQ) ? step + 1 : step;
            int ttn = dir ? (T_SEQ - 1 - sn) : sn;
            size_t basen = ((size_t)b * T_SEQ + ttn) * 960 + (size_t)dir * G3;
            if (tid < H) {
                nxr = xw[basen + tid];
                nxz = xw[basen + H + tid];
                nxn = xw[basen + 2 * H + tid];
            }
        }
        // two 160-dots sharing each broadcast h read
        float a0 = 0.f, a1 = 0.f, a2 = 0.f, a3 = 0.f;
        float c0 = 0.f, c1 = 0.f, c2 = 0.f, c3 = 0.f;
        {
            const half8_t* hp8 = reinterpret_cast<const half8_t*>(h_h);
            half8_t h;
            h = hp8[0];  dot8(h, wa0,  a0,a1,a2,a3); dot8(h, wb0,  c0,c1,c2,c3);
            h = hp8[1];  dot8(h, wa1,  a0,a1,a2,a3); dot8(h, wb1,  c0,c1,c2,c3);
            h = hp8[2];  dot8(h, wa2,  a0,a1,a2,a3); dot8(h, wb2,  c0,c1,c2,c3);
            h = hp8[3];  dot8(h, wa3,  a0,a1,a2,a3); dot8(h, wb3,  c0,c1,c2,c3);
            h = hp8[4];  dot8(h, wa4,  a0,a1,a2,a3); dot8(h, wb4,  c0,c1,c2,c3);
            h = hp8[5];  dot8(h, wa5,  a0,a1,a2,a3); dot8(h, wb5,  c0,c1,c2,c3);
            h = hp8[6];  dot8(h, wa6,  a0,a1,a2,a3); dot8(h, wb6,  c0,c1,c2,c3);
            h = hp8[7];  dot8(h, wa7,  a0,a1,a2,a3); dot8(h, wb7,  c0,c1,c2,c3);
            h = hp8[8];  dot8(h, wa8,  a0,a1,a2,a3); dot8(h, wb8,  c0,c1,c2,c3);
            h = hp8[9];  dot8(h, wa9,  a0,a1,a2,a3); dot8(h, wb9,  c0,c1,c2,c3);
            h = hp8[10]; dot8(h, wa10, a0,a1,a2,a3); dot8(h, wb10, c0,c1,c2,c3);
            h = hp8[11]; dot8(h, wa11, a0,a1,a2,a3); dot8(h, wb11, c0,c1,c2,c3);
            h = hp8[12]; dot8(h, wa12, a0,a1,a2,a3); dot8(h, wb12, c0,c1,c2,c3);
            h = hp8[13]; dot8(h, wa13, a0,a1,a2,a3); dot8(h, wb13, c0,c1,c2,c3);
            h = hp8[14]; dot8(h, wa14, a0,a1,a2,a3); dot8(h, wb14, c0,c1,c2,c3);
            h = hp8[15]; dot8(h, wa15, a0,a1,a2,a3); dot8(h, wb15, c0,c1,c2,c3);
            h = hp8[16]; dot8(h, wa16, a0,a1,a2,a3); dot8(h, wb16, c0,c1,c2,c3);
            h = hp8[17]; dot8(h, wa17, a0,a1,a2,a3); dot8(h, wb17, c0,c1,c2,c3);
            h = hp8[18]; dot8(h, wa18, a0,a1,a2,a3); dot8(h, wb18, c0,c1,c2,c3);
            h = hp8[19]; dot8(h, wa19, a0,a1,a2,a3); dot8(h, wb19, c0,c1,c2,c3);
        }
        if (rowact) {
            g_s[r0] = (a0 + a1) + (a2 + a3) + biasA;
            g_s[r1] = (c0 + c1) + (c2 + c3) + biasB;
        }
        __syncthreads();
        if (tid < H) {
            float rg = sigmoidf_(xr + g_s[tid]);
            float z  = sigmoidf_(xz + g_s[H + tid]);
            float n  = tanhf_(xn + rg * g_s[2 * H + tid]);
            float hn = (1.0f - z) * n + z * hcur;
            hcur = hn;
            h_h[tid] = (_Float16)hn;
            out[((size_t)b * T_SEQ + tt) * 320 + (size_t)dir * H + tid] = (_Float16)hn;
        }
        __syncthreads();
        xr = nxr; xz = nxz; xn = nxn;
    }
}

// ---------------- attn logits: [32768][4] = keys[tok][160] . score_w[h][160] + b ---
__global__ __launch_bounds__(256) void logits_kernel(
    const float* __restrict__ keys, const float* __restrict__ sw,
    const float* __restrict__ sb, float* __restrict__ out)
{
    int gid = blockIdx.x * 256 + threadIdx.x;
    int tok = gid >> 2, h = gid & 3;
    const float4* kr = reinterpret_cast<const float4*>(keys + (size_t)tok * H);
    const float4* wr = reinterpret_cast<const float4*>(sw + (size_t)h * H);
    float acc = 0.f;
    #pragma unroll
    for (int i = 0; i < H / 4; ++i) {
        float4 a = kr[i], w4 = wr[i];
        acc += a.x * w4.x + a.y * w4.y + a.z * w4.z + a.w * w4.w;
    }
    out[gid] = acc + sb[h];
}

// ---------------- epilogue: motion + softmax + pool + proj + LN + L2, 1 block/batch --
__global__ __launch_bounds__(512) void final_kernel(
    const float* __restrict__ x, const float* __restrict__ logits,
    const _Float16* __restrict__ seq, const float* __restrict__ proj_w,
    const float* __restrict__ proj_b, const float* __restrict__ ln_g,
    const float* __restrict__ ln_b, float* __restrict__ out)
{
    int b   = blockIdx.x;
    int tid = threadIdx.x;
    __shared__ float ms[T_SEQ];
    __shared__ float ss[T_SEQ];
    __shared__ __align__(16) float pooled[320];
    __shared__ float red[8];

    // Phase A: motion[t] = ||x[t]-x[t-1]||, m[0]=m[1]; standardize (ddof=1)
    {
        float m = 0.f;
        if (tid >= 1) {
            const float4* xc = reinterpret_cast<const float4*>(x + ((size_t)b * T_SEQ + tid) * DIN);
            const float4* xp = reinterpret_cast<const float4*>(x + ((size_t)b * T_SEQ + tid - 1) * DIN);
            float s = 0.f;
            #pragma unroll
            for (int i = 0; i < DIN / 4; ++i) {
                float4 a = xc[i], p = xp[i];
                float dx = a.x - p.x, dy = a.y - p.y, dz = a.z - p.z, dw = a.w - p.w;
                s += dx * dx + dy * dy + dz * dz + dw * dw;
            }
            m = sqrtf(s);
        }
        ms[tid] = m;
    }
    __syncthreads();
    if (tid == 0) ms[0] = ms[1];
    __syncthreads();
    float mv   = ms[tid];
    float mean = blockReduceSum(mv, red) * (1.0f / T_SEQ);
    float var  = blockReduceSum((mv - mean) * (mv - mean), red) * (1.0f / (T_SEQ - 1));
    float mstd = (mv - mean) / (sqrtf(var) + 1e-6f);

    // Phase B: 4 softmaxes over t; s[t] = mean_h weights
    float4 lg = *reinterpret_cast<const float4*>(logits + ((size_t)b * T_SEQ + tid) * 4);
    float l[4] = {lg.x + mstd, lg.y + mstd, lg.z + mstd, lg.w + mstd};
    float ssum = 0.f;
    #pragma unroll
    for (int h = 0; h < 4; ++h) {
        float mx = blockReduceMax(l[h], red);
        float e  = __expf(l[h] - mx);
        float se = blockReduceSum(e, red);
        float wv = e / se;
        ssum += wv;
    }
    float sv = ssum * 0.25f;
    ss[tid] = sv;
    out[16384 + b * T_SEQ + tid] = sv;   // output 1: weights.mean(axis=2)
    __syncthreads();

    // Phase C: pooled[d] = sum_t seq[b,t,d] * s[t]  (seq is f16)
    if (tid < 320) {
        float acc = 0.f;
        const _Float16* sp = seq + (size_t)b * T_SEQ * 320 + tid;
        #pragma unroll 4
        for (int t = 0; t < T_SEQ; ++t) acc += (float)sp[(size_t)t * 320] * ss[t];
        pooled[tid] = acc;
    }
    __syncthreads();

    // Phase D: embedding = pooled . proj_w^T + b ; LN ; L2-normalize
    float e = 0.f;
    if (tid < 256) {
        const float4* pw = reinterpret_cast<const float4*>(proj_w + (size_t)tid * 320);
        const float4* pl = reinterpret_cast<const float4*>(pooled);
        float acc = 0.f;
        #pragma unroll
        for (int i = 0; i < 80; ++i) {
            float4 w4 = pw[i], p4 = pl[i];
            acc += w4.x * p4.x + w4.y * p4.y + w4.z * p4.z + w4.w * p4.w;
        }
        e = acc + proj_b[tid];
    }
    float mu = blockReduceSum(tid < 256 ? e : 0.f, red) * (1.0f / 256);
    float dv = (tid < 256) ? (e - mu) : 0.f;
    float vr = blockReduceSum(dv * dv, red) * (1.0f / 256);
    float g  = 0.f;
    if (tid < 256) g = (e - mu) * rsqrtf(vr + 1e-5f) * ln_g[tid] + ln_b[tid];
    float nrm = sqrtf(blockReduceSum(g * g, red));
    nrm = fmaxf(nrm, 1e-12f);
    if (tid < 256) out[b * 256 + tid] = g / nrm;
}

extern "C" void kernel_launch(void* const* d_in, const int* in_sizes, int n_in,
                              void* d_out, int out_size, void* d_ws, size_t ws_size,
                              hipStream_t stream) {
    const float* x       = (const float*)d_in[0];
    const float* Wih0    = (const float*)d_in[1];
    const float* Whh0    = (const float*)d_in[2];
    const float* bih0    = (const float*)d_in[3];
    const float* bhh0    = (const float*)d_in[4];
    const float* Wih1    = (const float*)d_in[5];
    const float* Whh1    = (const float*)d_in[6];
    const float* bih1    = (const float*)d_in[7];
    const float* bhh1    = (const float*)d_in[8];
    const float* key_w   = (const float*)d_in[9];
    const float* key_b   = (const float*)d_in[10];
    const float* score_w = (const float*)d_in[11];
    const float* score_b = (const float*)d_in[12];
    const float* proj_w  = (const float*)d_in[13];
    const float* proj_b  = (const float*)d_in[14];
    const float* ln_g    = (const float*)d_in[15];
    const float* ln_b    = (const float*)d_in[16];

    const int M  = BATCH * T_SEQ;             // 32768
    const int NW = 2 * G3 * H;                // 153600 per GRU layer

    float* ws    = (float*)d_ws;
    float* xwbuf = ws;                        // 31457280 f
    float* keys  = xwbuf + 31457280;          //  5242880 f
    float* lgts  = keys + 5242880;            //   131072 f
    _Float16* h1_h   = (_Float16*)(lgts + 131072);   // 10485760 h = 5242880 f
    _Float16* seq_h  = h1_h + 10485760;              // 10485760 h
    _Float16* x_h    = seq_h + 10485760;             //  4194304 h
    _Float16* whh_h  = x_h + 4194304;                //   307200 h (both layers)
    _Float16* wih0_h = whh_h + 2 * NW;               //   122880 h
    _Float16* wih1_h = wih0_h + 122880;              //   307200 h
    _Float16* keyw_h = wih1_h + 307200;              //    51200 h
    float* outf  = (float*)d_out;

    // f32 -> f16 conversions (weights + x), all independent
    cvt_f2h_kernel<<<150, 256, 0, stream>>>(Whh0, whh_h, NW / 4);
    cvt_f2h_kernel<<<150, 256, 0, stream>>>(Whh1, whh_h + NW, NW / 4);
    cvt_f2h_kernel<<<120, 256, 0, stream>>>(Wih0, wih0_h, 122880 / 4);
    cvt_f2h_kernel<<<300, 256, 0, stream>>>(Wih1, wih1_h, 307200 / 4);
    cvt_f2h_kernel<<<50,  256, 0, stream>>>(key_w, keyw_h, 51200 / 4);
    cvt_f2h_kernel<<<2048, 256, 0, stream>>>(x, x_h, 4194304 / 4);

    gemm_f16_mfma_kernel<144><<<dim3(M / 64, 15), 256, 0, stream>>>(
        x_h, wih0_h, bih0, xwbuf, 960, 128, 0);
    gru_kernel<<<128, 256, 0, stream>>>(xwbuf, whh_h, bhh0, h1_h);
    gemm_f16_mfma_kernel<336><<<dim3(M / 64, 15), 256, 0, stream>>>(
        h1_h, wih1_h, bih1, xwbuf, 960, 320, 0);
    gru_kernel<<<128, 256, 0, stream>>>(xwbuf, whh_h + NW, bhh1, seq_h);
    gemm_f16_mfma_kernel<336><<<dim3(M / 64, 3), 256, 0, stream>>>(
        seq_h, keyw_h, key_b, keys, 160, 320, 1);
    logits_kernel<<<512, 256, 0, stream>>>(keys, score_w, score_b, lgts);
    final_kernel<<<64, 512, 0, stream>>>(x, lgts, seq_h, proj_w, proj_b, ln_g, ln_b, outf);
}